// Round 13
// baseline (103.028 us; speedup 1.0000x reference)
//
#include <hip/hip_runtime.h>
#include <hip/hip_bf16.h>

// B=32, H=W=96, D=128, WS=6, SS=3.
// Pipeline (split path, ws >= ~25.8 MB):
//  k_wprep : Wf,Wo -> transposed-bf16 padded LDS-images (34816 B each) in ws
//  k_tile3 : h (151 MB, read once) -> 3x3-tile sums S3 bf16 (8 MB ws)
//  k_tok   : S3 -> window means -> token_proj (bf16 MFMA) -> tok f32 (8 MB ws)
//  k_fuse  : tok -> fuse GEMM+LN+GELU -> ctx bf16, padded per-block blobs (8.9 MB ws)
//  k_out   : ctx+Wo image (pure uint4 copies) -> out GEMM+LN+GELU+mask+3x3 expand
// Fallback (small ws): monolithic k_fuse_out_mono (round-11 proven).
// Phase-additive model: grids are fully co-resident -> per-block phases ADD;
// the split cuts k_out's pre-store serial chain to ~8 us.
// S3 b-stride = 131072 elems. ctx block = blockIdx(b*16+m)*8704 u16.

#define DEVFN static __device__ __forceinline__

typedef __attribute__((ext_vector_type(8))) short bf16x8;
typedef __attribute__((ext_vector_type(16))) float f32x16;

DEVFN float gelu_exact(float x) {
  return 0.5f * x * (1.0f + erff(x * 0.70710678118654752f));
}

DEVFN unsigned short f2bf(float f) {  // RNE f32 -> bf16 bits (finite inputs)
  unsigned int u = __float_as_uint(f);
  u = (u + 0x7FFFu + ((u >> 16) & 1u)) >> 16;
  return (unsigned short)u;
}

DEVFN float bf2f(unsigned short u) {
  return __uint_as_float((unsigned int)u << 16);
}

DEVFN void add4(float4& a, const float4 v) {
  a.x += v.x; a.y += v.y; a.z += v.z; a.w += v.w;
}
DEVFN void fma4(float4& a, const float4 v, float m) {
  a.x = fmaf(v.x, m, a.x); a.y = fmaf(v.y, m, a.y);
  a.z = fmaf(v.z, m, a.z); a.w = fmaf(v.w, m, a.w);
}

// ---------------- Kernel 0: W -> bf16 transposed padded image ----------------
// grid 2 (block 0 = Wf, 1 = Wo), 512 thr. Image = exact byte image of wl:
// [n(128)][136 u16] rows (128 k + 8 pad) = 34816 B = 8704 u32 per W.
__global__ __launch_bounds__(512) void k_wprep(const float* __restrict__ Wf,
    const float* __restrict__ Wo, unsigned int* __restrict__ imgs) {
  const float* W = blockIdx.x ? Wo : Wf;
  unsigned int* img = imgs + (size_t)blockIdx.x * 8704;
  const int tid = threadIdx.x;
  #pragma unroll
  for (int p = 0; p < 4; ++p) {
    const int i = tid + p * 512;            // 0..2047: kpair x n4-chunk
    const int kp = i >> 5;                  // k pair 0..63
    const int n4 = (i & 31) * 4;
    const float4 r0 = *reinterpret_cast<const float4*>(W + (size_t)(2 * kp) * 128 + n4);
    const float4 r1 = *reinterpret_cast<const float4*>(W + (size_t)(2 * kp + 1) * 128 + n4);
    const float a0[4] = {r0.x, r0.y, r0.z, r0.w};
    const float a1[4] = {r1.x, r1.y, r1.z, r1.w};
    #pragma unroll
    for (int j = 0; j < 4; ++j)
      img[(n4 + j) * 68 + kp] =
          (unsigned int)f2bf(a0[j]) | ((unsigned int)f2bf(a1[j]) << 16);
  }
}

// ---------------- Kernel 1: 3x3-tile sums, bf16 output (unchanged) ----------
__global__ __launch_bounds__(512) void k_tile3(const float* __restrict__ h,
                                               unsigned short* __restrict__ S3) {
  const int b  = blockIdx.x >> 5;
  const int ry = blockIdx.x & 31;
  const int w    = threadIdx.x >> 6;
  const int lane = threadIdx.x & 63;
  const int half = lane >> 5;
  const int ch4  = (lane & 31) << 2;
  const float mlo = half ? 0.f : 1.f;
  const float mhi = 1.f - mlo;

  float4 acc[4];
  #pragma unroll
  for (int t = 0; t < 4; ++t) acc[t] = make_float4(0.f, 0.f, 0.f, 0.f);

  #pragma unroll
  for (int yy = 0; yy < 3; ++yy) {
    const float* rp =
        h + ((size_t)(b * 9216 + (3 * ry + yy) * 96 + 12 * w + half) * 128 + ch4);
    #pragma unroll
    for (int j = 0; j < 6; ++j) {        // col = 12w + 2j + half
      const float4 v = *reinterpret_cast<const float4*>(rp + j * 256);
      if (j == 0)      add4(acc[0], v);
      else if (j == 2) add4(acc[1], v);
      else if (j == 3) add4(acc[2], v);
      else if (j == 5) add4(acc[3], v);
      else if (j == 1) { fma4(acc[0], v, mlo); fma4(acc[1], v, mhi); }
      else             { fma4(acc[2], v, mlo); fma4(acc[3], v, mhi); }
    }
  }

  #pragma unroll
  for (int t = 0; t < 4; ++t) {
    float4 s = acc[t];
    s.x += __shfl_xor(s.x, 32, 64);
    s.y += __shfl_xor(s.y, 32, 64);
    s.z += __shfl_xor(s.z, 32, 64);
    s.w += __shfl_xor(s.w, 32, 64);
    if (half == 0) {
      short4 pk;
      pk.x = (short)f2bf(s.x); pk.y = (short)f2bf(s.y);
      pk.z = (short)f2bf(s.z); pk.w = (short)f2bf(s.w);
      *reinterpret_cast<short4*>(
          &S3[((size_t)(b * 32 + ry) * 32 + 4 * w + t) * 128 + ch4]) = pk;
    }
  }
}

// ---------------- MFMA helpers ----------------
// Full-W stage with cvt (k_tok / fallback): f32 [k][n] -> bf16 LDS [n][136].
DEVFN void stage_w_bf(unsigned short* __restrict__ wl,
                      const float* __restrict__ W, int tid) {
  #pragma unroll
  for (int p = 0; p < 4; ++p) {
    const int i = tid + p * 512;
    const int kp = i >> 5;
    const int n4 = (i & 31) * 4;
    const float4 r0 = *reinterpret_cast<const float4*>(W + (size_t)(2 * kp) * 128 + n4);
    const float4 r1 = *reinterpret_cast<const float4*>(W + (size_t)(2 * kp + 1) * 128 + n4);
    const float a0[4] = {r0.x, r0.y, r0.z, r0.w};
    const float a1[4] = {r1.x, r1.y, r1.z, r1.w};
    #pragma unroll
    for (int j = 0; j < 4; ++j) {
      const unsigned int pk =
          (unsigned int)f2bf(a0[j]) | ((unsigned int)f2bf(a1[j]) << 16);
      *reinterpret_cast<unsigned int*>(&wl[(n4 + j) * 136 + 2 * kp]) = pk;
    }
  }
}

// 8-step (K=128) MFMA tile, stride-16 frags.
DEVFN f32x16 mfma_tile(const unsigned short* __restrict__ xrow,
                       const unsigned short* __restrict__ wrow) {
  f32x16 acc;
  #pragma unroll
  for (int r = 0; r < 16; ++r) acc[r] = 0.f;
  #pragma unroll
  for (int kk = 0; kk < 8; ++kk) {
    const bf16x8 a = *reinterpret_cast<const bf16x8*>(xrow + kk * 16);
    const bf16x8 bb = *reinterpret_cast<const bf16x8*>(wrow + kk * 16);
    acc = __builtin_amdgcn_mfma_f32_32x32x16_bf16(a, bb, acc, 0, 0, 0);
  }
  return acc;
}

// C/D layout (verified m74/m101): col = lane&31, row = (r&3)+8*(r>>2)+4*(l>>5).
DEVFN void write_raw(float* __restrict__ raw, const f32x16 acc,
                     int tg, int cg, int lane) {
  const int n  = cg * 32 + (lane & 31);
  const int mb = tg * 32 + 4 * (lane >> 5);
  #pragma unroll
  for (int r = 0; r < 16; ++r) {
    const int mm = mb + (r & 3) + 8 * (r >> 2);
    raw[mm * 132 + n] = acc[r];
  }
}

// ---------------- Kernel 2: window gather + token_proj (unchanged) ----------
__global__ __launch_bounds__(512) void k_tok(const unsigned short* __restrict__ S3,
    const float* __restrict__ Wt, const float* __restrict__ bt,
    const float* __restrict__ gt, const float* __restrict__ bgt,
    float* __restrict__ tok) {
  __shared__ __align__(16) unsigned short xs_bf[64 * 136];
  __shared__ __align__(16) unsigned short wl[128 * 136];
  float* raw = reinterpret_cast<float*>(wl);

  const int tid = threadIdx.x;
  const int t0 = blockIdx.x * 64;
  const int s  = t0 >> 13;
  const int b  = (t0 >> 8) & 31;
  const int wyx = t0 & 255;

  const unsigned short* Sb = S3 + (size_t)b * 131072;
  #pragma unroll
  for (int p = 0; p < 2; ++p) {
    const int i = tid + p * 512;
    const int tt = i >> 4, c8 = (i & 15) * 8;
    const int idx = wyx + tt;
    const int wy = idx >> 4, wx = idx & 15;
    int ry0, ry1, c0, c1;
    if (s == 0) { ry0 = 2 * wy;     ry1 = 2 * wy + 1;        c0 = 2 * wx;     c1 = 2 * wx + 1; }
    else        { ry0 = 2 * wy + 1; ry1 = (2 * wy + 2) & 31; c0 = 2 * wx + 1; c1 = (2 * wx + 2) & 31; }
    const bf16x8 v00 = *reinterpret_cast<const bf16x8*>(Sb + ((size_t)(ry0 * 32 + c0) * 128 + c8));
    const bf16x8 v01 = *reinterpret_cast<const bf16x8*>(Sb + ((size_t)(ry0 * 32 + c1) * 128 + c8));
    const bf16x8 v10 = *reinterpret_cast<const bf16x8*>(Sb + ((size_t)(ry1 * 32 + c0) * 128 + c8));
    const bf16x8 v11 = *reinterpret_cast<const bf16x8*>(Sb + ((size_t)(ry1 * 32 + c1) * 128 + c8));
    bf16x8 pk;
    #pragma unroll
    for (int j = 0; j < 8; ++j) {
      const float sum = bf2f((unsigned short)v00[j]) + bf2f((unsigned short)v01[j]) +
                        bf2f((unsigned short)v10[j]) + bf2f((unsigned short)v11[j]);
      pk[j] = (short)f2bf(sum * (1.f / 36.f));
    }
    *reinterpret_cast<bf16x8*>(&xs_bf[tt * 136 + c8]) = pk;
  }
  stage_w_bf(wl, Wt, tid);
  __syncthreads();

  const int lane = tid & 63;
  const int w = tid >> 6;
  const int tg = w >> 2, cg = w & 3;
  const unsigned short* xrow = &xs_bf[(tg * 32 + (lane & 31)) * 136 + 8 * (lane >> 5)];
  const unsigned short* wrow = &wl[(cg * 32 + (lane & 31)) * 136 + 8 * (lane >> 5)];

  const f32x16 acc = mfma_tile(xrow, wrow);
  __syncthreads();
  write_raw(raw, acc, tg, cg, lane);
  __syncthreads();

  {
    const int tt = tid >> 3, cb = tid & 7;
    float v[16];
    float s2 = 0.f, q = 0.f;
    #pragma unroll
    for (int i = 0; i < 4; ++i) {
      const int col = 4 * cb + 32 * i;
      const float4 rv = *reinterpret_cast<const float4*>(&raw[tt * 132 + col]);
      const float4 bv = *reinterpret_cast<const float4*>(bt + col);
      v[4 * i + 0] = rv.x + bv.x; v[4 * i + 1] = rv.y + bv.y;
      v[4 * i + 2] = rv.z + bv.z; v[4 * i + 3] = rv.w + bv.w;
    }
    #pragma unroll
    for (int e = 0; e < 16; ++e) { s2 += v[e]; q += v[e] * v[e]; }
    s2 += __shfl_xor(s2, 1, 8); q += __shfl_xor(q, 1, 8);
    s2 += __shfl_xor(s2, 2, 8); q += __shfl_xor(q, 2, 8);
    s2 += __shfl_xor(s2, 4, 8); q += __shfl_xor(q, 4, 8);
    const float mean = s2 * (1.f / 128.f);
    const float var  = q * (1.f / 128.f) - mean * mean;
    const float inv  = rsqrtf(var + 1e-5f);
    #pragma unroll
    for (int i = 0; i < 4; ++i) {
      const int col = 4 * cb + 32 * i;
      const float4 gv = *reinterpret_cast<const float4*>(gt + col);
      const float4 ev = *reinterpret_cast<const float4*>(bgt + col);
      float4 ov;
      ov.x = gelu_exact((v[4 * i + 0] - mean) * inv * gv.x + ev.x);
      ov.y = gelu_exact((v[4 * i + 1] - mean) * inv * gv.y + ev.y);
      ov.z = gelu_exact((v[4 * i + 2] - mean) * inv * gv.z + ev.z);
      ov.w = gelu_exact((v[4 * i + 3] - mean) * inv * gv.w + ev.w);
      *reinterpret_cast<float4*>(tok + (size_t)(t0 + tt) * 128 + col) = ov;
    }
  }
}

// ---------------- Kernel 3a: fuse GEMM -> ctx bf16 (split path) ----------------
// grid = 32*16 (b, m), 512 thr = 8 waves; ctx blob = blockIdx * 8704 u16.
__global__ __launch_bounds__(512) void k_fuse(const float* __restrict__ tok,
    const unsigned int* __restrict__ wimg,
    const float* __restrict__ bfv, const float* __restrict__ gf,
    const float* __restrict__ bgf, unsigned short* __restrict__ ctx) {
  __shared__ __align__(16) unsigned short xs_bf[64 * 136];
  __shared__ __align__(16) unsigned short wl[128 * 136];
  float* raw = reinterpret_cast<float*>(wl);

  const int tid = threadIdx.x;
  const int b = blockIdx.x >> 4;
  const int m = blockIdx.x & 15;
  const int lane = tid & 63;
  const int w = tid >> 6;
  const int tg = w >> 2, cg = w & 3;

  const float* tokR = tok + (size_t)b * 32768 + (size_t)m * 2048;
  const float* tokS = tok + 1048576 + (size_t)b * 32768;

  // gather reg+sh -> bf16 xs ; Wf image -> wl (pure copy, 2176 uint4).
  #pragma unroll
  for (int p = 0; p < 2; ++p) {
    const int i = tid + p * 512;
    const int t = i >> 4, c8 = (i & 15) * 8;
    const int gx = t & 31, gy = 2 * m + (t >> 5);
    const int wx  = gx >> 1;
    const int wxs = ((gx + 31) & 31) >> 1;
    const int wys = ((gy + 31) & 31) >> 1;
    const float* pr = tokR + (size_t)wx * 128 + c8;
    const float* ps = tokS + (size_t)(wys * 16 + wxs) * 128 + c8;
    bf16x8 pk;
    #pragma unroll
    for (int j = 0; j < 8; ++j)
      pk[j] = (short)f2bf(pr[j] + ps[j]);
    *reinterpret_cast<bf16x8*>(&xs_bf[t * 136 + c8]) = pk;
  }
  for (int i = tid; i < 2176; i += 512)
    reinterpret_cast<uint4*>(wl)[i] = reinterpret_cast<const uint4*>(wimg)[i];
  __syncthreads();

  const unsigned short* xrow = &xs_bf[(tg * 32 + (lane & 31)) * 136 + 8 * (lane >> 5)];
  const unsigned short* wrow = &wl[(cg * 32 + (lane & 31)) * 136 + 8 * (lane >> 5)];

  const f32x16 acc = mfma_tile(xrow, wrow);
  __syncthreads();
  write_raw(raw, acc, tg, cg, lane);
  __syncthreads();

  // LN+GELU(ctx) -> bf16 ctx blob (global). 8 threads/token.
  unsigned short* cblk = ctx + (size_t)blockIdx.x * 8704;
  {
    const int tt = tid >> 3, cb = tid & 7;
    float v[16];
    float s = 0.f, q = 0.f;
    #pragma unroll
    for (int i = 0; i < 4; ++i) {
      const int col = 4 * cb + 32 * i;
      const float4 rv = *reinterpret_cast<const float4*>(&raw[tt * 132 + col]);
      const float4 bv = *reinterpret_cast<const float4*>(bfv + col);
      v[4 * i + 0] = rv.x + bv.x; v[4 * i + 1] = rv.y + bv.y;
      v[4 * i + 2] = rv.z + bv.z; v[4 * i + 3] = rv.w + bv.w;
    }
    #pragma unroll
    for (int e = 0; e < 16; ++e) { s += v[e]; q += v[e] * v[e]; }
    s += __shfl_xor(s, 1, 8); q += __shfl_xor(q, 1, 8);
    s += __shfl_xor(s, 2, 8); q += __shfl_xor(q, 2, 8);
    s += __shfl_xor(s, 4, 8); q += __shfl_xor(q, 4, 8);
    const float mean = s * (1.f / 128.f);
    const float var  = q * (1.f / 128.f) - mean * mean;
    const float inv  = rsqrtf(var + 1e-5f);
    #pragma unroll
    for (int i = 0; i < 4; ++i) {
      const int col = 4 * cb + 32 * i;
      const float4 gv = *reinterpret_cast<const float4*>(gf + col);
      const float4 ev = *reinterpret_cast<const float4*>(bgf + col);
      short4 pk;
      pk.x = (short)f2bf(gelu_exact((v[4 * i + 0] - mean) * inv * gv.x + ev.x));
      pk.y = (short)f2bf(gelu_exact((v[4 * i + 1] - mean) * inv * gv.y + ev.y));
      pk.z = (short)f2bf(gelu_exact((v[4 * i + 2] - mean) * inv * gv.z + ev.z));
      pk.w = (short)f2bf(gelu_exact((v[4 * i + 3] - mean) * inv * gv.w + ev.w));
      *reinterpret_cast<short4*>(&cblk[tt * 136 + col]) = pk;
    }
  }
}

// ---------------- Kernel 3b: out_proj + expand (split path) ----------------
// grid = 32*16 (b, m), 512 thr. Pre-store chain = 2 uint4 copies + 8 MFMA.
__global__ __launch_bounds__(512) void k_out(const unsigned short* __restrict__ ctx,
    const unsigned int* __restrict__ wimg,
    const float* __restrict__ bo, const float* __restrict__ go,
    const float* __restrict__ bgo,
    const float* __restrict__ mask, float* __restrict__ out) {
  __shared__ __align__(16) unsigned short xs_bf[64 * 136];
  __shared__ __align__(16) unsigned short wl[128 * 136];
  float* raw = reinterpret_cast<float*>(wl);

  const int tid = threadIdx.x;
  const int b = blockIdx.x >> 4;
  const int m = blockIdx.x & 15;
  const int lane = tid & 63;
  const int w = tid >> 6;
  const int tg = w >> 2, cg = w & 3;

  const uint4* csrc = reinterpret_cast<const uint4*>(ctx + (size_t)blockIdx.x * 8704);
  for (int i = tid; i < 1088; i += 512)
    reinterpret_cast<uint4*>(xs_bf)[i] = csrc[i];
  for (int i = tid; i < 2176; i += 512)
    reinterpret_cast<uint4*>(wl)[i] = reinterpret_cast<const uint4*>(wimg)[i];
  __syncthreads();

  const unsigned short* xrow = &xs_bf[(tg * 32 + (lane & 31)) * 136 + 8 * (lane >> 5)];
  const unsigned short* wrow = &wl[(cg * 32 + (lane & 31)) * 136 + 8 * (lane >> 5)];

  const f32x16 acc = mfma_tile(xrow, wrow);
  __syncthreads();
  write_raw(raw, acc, tg, cg, lane);
  __syncthreads();

  // LN+GELU(out) + mask + 3x3 expand stores.
  {
    const int tt = tid >> 3, cb = tid & 7;
    float v[16];
    float s = 0.f, q = 0.f;
    #pragma unroll
    for (int i = 0; i < 4; ++i) {
      const int col = 4 * cb + 32 * i;
      const float4 rv = *reinterpret_cast<const float4*>(&raw[tt * 132 + col]);
      const float4 bv = *reinterpret_cast<const float4*>(bo + col);
      v[4 * i + 0] = rv.x + bv.x; v[4 * i + 1] = rv.y + bv.y;
      v[4 * i + 2] = rv.z + bv.z; v[4 * i + 3] = rv.w + bv.w;
    }
    #pragma unroll
    for (int e = 0; e < 16; ++e) { s += v[e]; q += v[e] * v[e]; }
    s += __shfl_xor(s, 1, 8); q += __shfl_xor(q, 1, 8);
    s += __shfl_xor(s, 2, 8); q += __shfl_xor(q, 2, 8);
    s += __shfl_xor(s, 4, 8); q += __shfl_xor(q, 4, 8);
    const float mean = s * (1.f / 128.f);
    const float var  = q * (1.f / 128.f) - mean * mean;
    const float inv  = rsqrtf(var + 1e-5f);
    #pragma unroll
    for (int i = 0; i < 4; ++i) {
      const int col = 4 * cb + 32 * i;
      const float4 gv = *reinterpret_cast<const float4*>(go + col);
      const float4 ev = *reinterpret_cast<const float4*>(bgo + col);
      v[4 * i + 0] = gelu_exact((v[4 * i + 0] - mean) * inv * gv.x + ev.x);
      v[4 * i + 1] = gelu_exact((v[4 * i + 1] - mean) * inv * gv.y + ev.y);
      v[4 * i + 2] = gelu_exact((v[4 * i + 2] - mean) * inv * gv.z + ev.z);
      v[4 * i + 3] = gelu_exact((v[4 * i + 3] - mean) * inv * gv.w + ev.w);
    }
    const int gx = tt & 31, gy = 2 * m + (tt >> 5);
    #pragma unroll
    for (int py = 0; py < 3; ++py) {
      const int y = 3 * gy + py;
      #pragma unroll
      for (int px = 0; px < 3; ++px) {
        const int x = 3 * gx + px;
        const size_t pix = (size_t)b * 9216 + (size_t)y * 96 + x;
        const float mv = mask[pix];
        #pragma unroll
        for (int i = 0; i < 4; ++i) {
          const int col = 4 * cb + 32 * i;
          *reinterpret_cast<float4*>(out + pix * 128 + col) =
              make_float4(v[4 * i + 0] * mv, v[4 * i + 1] * mv,
                          v[4 * i + 2] * mv, v[4 * i + 3] * mv);
        }
      }
    }
  }
}

// -------- Fallback: monolithic fuse+out (round-11 proven, 91.6 us path) -----
__global__ __launch_bounds__(512) void k_fuse_out_mono(const float* __restrict__ tok,
    const float* __restrict__ Wf, const float* __restrict__ bfv,
    const float* __restrict__ gf, const float* __restrict__ bgf,
    const float* __restrict__ Wo, const float* __restrict__ bo,
    const float* __restrict__ go, const float* __restrict__ bgo,
    const float* __restrict__ mask, float* __restrict__ out) {
  __shared__ __align__(16) unsigned short xs_bf[64 * 136];
  __shared__ __align__(16) unsigned short wl[128 * 136];
  float* raw = reinterpret_cast<float*>(wl);

  const int tid = threadIdx.x;
  const int b = blockIdx.x >> 4;
  const int m = blockIdx.x & 15;
  const int lane = tid & 63;
  const int w = tid >> 6;
  const int tg = w >> 2, cg = w & 3;

  const float* tokR = tok + (size_t)b * 32768 + (size_t)m * 2048;
  const float* tokS = tok + 1048576 + (size_t)b * 32768;

  #pragma unroll
  for (int p = 0; p < 2; ++p) {
    const int i = tid + p * 512;
    const int t = i >> 4, c8 = (i & 15) * 8;
    const int gx = t & 31, gy = 2 * m + (t >> 5);
    const int wx  = gx >> 1;
    const int wxs = ((gx + 31) & 31) >> 1;
    const int wys = ((gy + 31) & 31) >> 1;
    const float* pr = tokR + (size_t)wx * 128 + c8;
    const float* ps = tokS + (size_t)(wys * 16 + wxs) * 128 + c8;
    bf16x8 pk;
    #pragma unroll
    for (int j = 0; j < 8; ++j)
      pk[j] = (short)f2bf(pr[j] + ps[j]);
    *reinterpret_cast<bf16x8*>(&xs_bf[t * 136 + c8]) = pk;
  }
  stage_w_bf(wl, Wf, tid);
  __syncthreads();

  const unsigned short* xrow = &xs_bf[(tg * 32 + (lane & 31)) * 136 + 8 * (lane >> 5)];
  const unsigned short* wrow = &wl[(cg * 32 + (lane & 31)) * 136 + 8 * (lane >> 5)];

  const f32x16 acc1 = mfma_tile(xrow, wrow);
  __syncthreads();
  write_raw(raw, acc1, tg, cg, lane);
  __syncthreads();

  {
    const int tt = tid >> 3, cb = tid & 7;
    float v[16];
    float s = 0.f, q = 0.f;
    #pragma unroll
    for (int i = 0; i < 4; ++i) {
      const int col = 4 * cb + 32 * i;
      const float4 rv = *reinterpret_cast<const float4*>(&raw[tt * 132 + col]);
      const float4 bv = *reinterpret_cast<const float4*>(bfv + col);
      v[4 * i + 0] = rv.x + bv.x; v[4 * i + 1] = rv.y + bv.y;
      v[4 * i + 2] = rv.z + bv.z; v[4 * i + 3] = rv.w + bv.w;
    }
    #pragma unroll
    for (int e = 0; e < 16; ++e) { s += v[e]; q += v[e] * v[e]; }
    s += __shfl_xor(s, 1, 8); q += __shfl_xor(q, 1, 8);
    s += __shfl_xor(s, 2, 8); q += __shfl_xor(q, 2, 8);
    s += __shfl_xor(s, 4, 8); q += __shfl_xor(q, 4, 8);
    const float mean = s * (1.f / 128.f);
    const float var  = q * (1.f / 128.f) - mean * mean;
    const float inv  = rsqrtf(var + 1e-5f);
    __syncthreads();
    #pragma unroll
    for (int i = 0; i < 4; ++i) {
      const int col = 4 * cb + 32 * i;
      const float4 gv = *reinterpret_cast<const float4*>(gf + col);
      const float4 ev = *reinterpret_cast<const float4*>(bgf + col);
      short4 pk;
      pk.x = (short)f2bf(gelu_exact((v[4 * i + 0] - mean) * inv * gv.x + ev.x));
      pk.y = (short)f2bf(gelu_exact((v[4 * i + 1] - mean) * inv * gv.y + ev.y));
      pk.z = (short)f2bf(gelu_exact((v[4 * i + 2] - mean) * inv * gv.z + ev.z));
      pk.w = (short)f2bf(gelu_exact((v[4 * i + 3] - mean) * inv * gv.w + ev.w));
      *reinterpret_cast<short4*>(&xs_bf[tt * 136 + col]) = pk;
    }
  }
  __syncthreads();
  stage_w_bf(wl, Wo, tid);
  __syncthreads();

  const f32x16 acc2 = mfma_tile(xrow, wrow);
  __syncthreads();
  write_raw(raw, acc2, tg, cg, lane);
  __syncthreads();

  {
    const int tt = tid >> 3, cb = tid & 7;
    float v[16];
    float s = 0.f, q = 0.f;
    #pragma unroll
    for (int i = 0; i < 4; ++i) {
      const int col = 4 * cb + 32 * i;
      const float4 rv = *reinterpret_cast<const float4*>(&raw[tt * 132 + col]);
      const float4 bv = *reinterpret_cast<const float4*>(bo + col);
      v[4 * i + 0] = rv.x + bv.x; v[4 * i + 1] = rv.y + bv.y;
      v[4 * i + 2] = rv.z + bv.z; v[4 * i + 3] = rv.w + bv.w;
    }
    #pragma unroll
    for (int e = 0; e < 16; ++e) { s += v[e]; q += v[e] * v[e]; }
    s += __shfl_xor(s, 1, 8); q += __shfl_xor(q, 1, 8);
    s += __shfl_xor(s, 2, 8); q += __shfl_xor(q, 2, 8);
    s += __shfl_xor(s, 4, 8); q += __shfl_xor(q, 4, 8);
    const float mean = s * (1.f / 128.f);
    const float var  = q * (1.f / 128.f) - mean * mean;
    const float inv  = rsqrtf(var + 1e-5f);
    #pragma unroll
    for (int i = 0; i < 4; ++i) {
      const int col = 4 * cb + 32 * i;
      const float4 gv = *reinterpret_cast<const float4*>(go + col);
      const float4 ev = *reinterpret_cast<const float4*>(bgo + col);
      v[4 * i + 0] = gelu_exact((v[4 * i + 0] - mean) * inv * gv.x + ev.x);
      v[4 * i + 1] = gelu_exact((v[4 * i + 1] - mean) * inv * gv.y + ev.y);
      v[4 * i + 2] = gelu_exact((v[4 * i + 2] - mean) * inv * gv.z + ev.z);
      v[4 * i + 3] = gelu_exact((v[4 * i + 3] - mean) * inv * gv.w + ev.w);
    }
    const int gx = tt & 31, gy = 2 * m + (tt >> 5);
    #pragma unroll
    for (int py = 0; py < 3; ++py) {
      const int y = 3 * gy + py;
      #pragma unroll
      for (int px = 0; px < 3; ++px) {
        const int x = 3 * gx + px;
        const size_t pix = (size_t)b * 9216 + (size_t)y * 96 + x;
        const float mv = mask[pix];
        #pragma unroll
        for (int i = 0; i < 4; ++i) {
          const int col = 4 * cb + 32 * i;
          *reinterpret_cast<float4*>(out + pix * 128 + col) =
              make_float4(v[4 * i + 0] * mv, v[4 * i + 1] * mv,
                          v[4 * i + 2] * mv, v[4 * i + 3] * mv);
        }
      }
    }
  }
}

extern "C" void kernel_launch(void* const* d_in, const int* in_sizes, int n_in,
                              void* d_out, int out_size, void* d_ws, size_t ws_size,
                              hipStream_t stream) {
  (void)in_sizes; (void)n_in; (void)out_size;
  const float* h    = (const float*)d_in[0];
  const float* mask = (const float*)d_in[1];
  const float* Wt   = (const float*)d_in[2];
  const float* bt   = (const float*)d_in[3];
  const float* gt   = (const float*)d_in[4];
  const float* bgt  = (const float*)d_in[5];
  const float* Wf   = (const float*)d_in[6];
  const float* bfv  = (const float*)d_in[7];
  const float* gf   = (const float*)d_in[8];
  const float* bgf  = (const float*)d_in[9];
  const float* Wo   = (const float*)d_in[10];
  const float* bo   = (const float*)d_in[11];
  const float* go   = (const float*)d_in[12];
  const float* bgo  = (const float*)d_in[13];

  unsigned short* S3 = (unsigned short*)d_ws;                          // 8 MiB
  float* tok = (float*)((char*)d_ws + (size_t)8 * 1024 * 1024);        // 8 MiB
  float* out = (float*)d_out;

  // Split-path scratch: imgs @16MiB (68 KiB used), ctx @16MiB+128KiB (8.5 MiB).
  const size_t NEED = (size_t)16 * 1024 * 1024 + 131072 + (size_t)512 * 17408;

  hipLaunchKernelGGL(k_tile3, dim3(1024), dim3(512), 0, stream, h, S3);
  hipLaunchKernelGGL(k_tok, dim3(256), dim3(512), 0, stream,
                     S3, Wt, bt, gt, bgt, tok);

  if (ws_size >= NEED) {
    unsigned int* imgs = (unsigned int*)((char*)d_ws + (size_t)16 * 1024 * 1024);
    unsigned short* ctx =
        (unsigned short*)((char*)d_ws + (size_t)16 * 1024 * 1024 + 131072);
    hipLaunchKernelGGL(k_wprep, dim3(2), dim3(512), 0, stream, Wf, Wo, imgs);
    hipLaunchKernelGGL(k_fuse, dim3(512), dim3(512), 0, stream,
                       tok, imgs, bfv, gf, bgf, ctx);
    hipLaunchKernelGGL(k_out, dim3(512), dim3(512), 0, stream,
                       ctx, imgs + 8704, bo, go, bgo, mask, out);
  } else {
    hipLaunchKernelGGL(k_fuse_out_mono, dim3(512), dim3(512), 0, stream,
                       tok, Wf, bfv, gf, bgf, Wo, bo, go, bgo, mask, out);
  }
}

// Round 14
// 88.164 us; speedup vs baseline: 1.1686x; 1.1686x over previous
//
#include <hip/hip_runtime.h>
#include <hip/hip_bf16.h>

// B=32, H=W=96, D=128, WS=6, SS=3.
// Pipeline (round-11 proven structure, surgical VALU cuts only):
//  k_tile3   : h (151 MB, read ONCE) -> 3x3-tile sums S3 bf16 (8 MB ws)
//  k_tok     : S3 -> window means -> token_proj (bf16 MFMA) -> tok f32 (8 MB ws)
//  k_fuse_out: tok -> fuse + out_proj (bf16 MFMA) -> 3x3 expand -> out f32
// Changes vs round 11: (1) gelu via tanh-form sigmoid identity (3 FMA + HW
// exp + div) instead of erff (branchy ~40cyc); max abs dev ~3e-3, margin 3x.
// (2) removed redundant inner barrier in fuse LN phase. Nothing else touched.
// S3 b-stride = 131072 elems (32*32*128).

#define DEVFN static __device__ __forceinline__

typedef __attribute__((ext_vector_type(8))) short bf16x8;
typedef __attribute__((ext_vector_type(16))) float f32x16;

DEVFN float gelu_fast(float x) {
  // tanh-form GELU == x * sigmoid(2*0.7978845608*(x + 0.044715 x^3))
  const float u = 1.5957691216057308f * (x + 0.044715f * x * x * x);
  return x / (1.0f + __expf(-u));
}

DEVFN unsigned short f2bf(float f) {  // RNE f32 -> bf16 bits (finite inputs)
  unsigned int u = __float_as_uint(f);
  u = (u + 0x7FFFu + ((u >> 16) & 1u)) >> 16;
  return (unsigned short)u;
}

DEVFN float bf2f(unsigned short u) {
  return __uint_as_float((unsigned int)u << 16);
}

DEVFN void add4(float4& a, const float4 v) {
  a.x += v.x; a.y += v.y; a.z += v.z; a.w += v.w;
}
DEVFN void fma4(float4& a, const float4 v, float m) {
  a.x = fmaf(v.x, m, a.x); a.y = fmaf(v.y, m, a.y);
  a.z = fmaf(v.z, m, a.z); a.w = fmaf(v.w, m, a.w);
}

// ---------------- Kernel 1: 3x3-tile sums, bf16 output ----------------
__global__ __launch_bounds__(512) void k_tile3(const float* __restrict__ h,
                                               unsigned short* __restrict__ S3) {
  const int b  = blockIdx.x >> 5;
  const int ry = blockIdx.x & 31;
  const int w    = threadIdx.x >> 6;
  const int lane = threadIdx.x & 63;
  const int half = lane >> 5;
  const int ch4  = (lane & 31) << 2;
  const float mlo = half ? 0.f : 1.f;
  const float mhi = 1.f - mlo;

  float4 acc[4];
  #pragma unroll
  for (int t = 0; t < 4; ++t) acc[t] = make_float4(0.f, 0.f, 0.f, 0.f);

  #pragma unroll
  for (int yy = 0; yy < 3; ++yy) {
    const float* rp =
        h + ((size_t)(b * 9216 + (3 * ry + yy) * 96 + 12 * w + half) * 128 + ch4);
    #pragma unroll
    for (int j = 0; j < 6; ++j) {        // col = 12w + 2j + half
      const float4 v = *reinterpret_cast<const float4*>(rp + j * 256);
      if (j == 0)      add4(acc[0], v);
      else if (j == 2) add4(acc[1], v);
      else if (j == 3) add4(acc[2], v);
      else if (j == 5) add4(acc[3], v);
      else if (j == 1) { fma4(acc[0], v, mlo); fma4(acc[1], v, mhi); }
      else             { fma4(acc[2], v, mlo); fma4(acc[3], v, mhi); }
    }
  }

  #pragma unroll
  for (int t = 0; t < 4; ++t) {
    float4 s = acc[t];
    s.x += __shfl_xor(s.x, 32, 64);
    s.y += __shfl_xor(s.y, 32, 64);
    s.z += __shfl_xor(s.z, 32, 64);
    s.w += __shfl_xor(s.w, 32, 64);
    if (half == 0) {
      short4 pk;
      pk.x = (short)f2bf(s.x); pk.y = (short)f2bf(s.y);
      pk.z = (short)f2bf(s.z); pk.w = (short)f2bf(s.w);
      *reinterpret_cast<short4*>(
          &S3[((size_t)(b * 32 + ry) * 32 + 4 * w + t) * 128 + ch4]) = pk;
    }
  }
}

// ---------------- MFMA helpers ----------------
// Stage W (f32 global, [k][n]) -> transposed bf16 LDS Wl[n][k], rows padded
// to 136 elems for conflict-free b128 frag reads.
DEVFN void stage_w_bf(unsigned short* __restrict__ wl,
                      const float* __restrict__ W, int tid) {
  #pragma unroll
  for (int p = 0; p < 4; ++p) {
    const int i = tid + p * 512;
    const int kp = i >> 5;
    const int n4 = (i & 31) * 4;
    const float4 r0 = *reinterpret_cast<const float4*>(W + (size_t)(2 * kp) * 128 + n4);
    const float4 r1 = *reinterpret_cast<const float4*>(W + (size_t)(2 * kp + 1) * 128 + n4);
    const float a0[4] = {r0.x, r0.y, r0.z, r0.w};
    const float a1[4] = {r1.x, r1.y, r1.z, r1.w};
    #pragma unroll
    for (int j = 0; j < 4; ++j) {
      const unsigned int pk =
          (unsigned int)f2bf(a0[j]) | ((unsigned int)f2bf(a1[j]) << 16);
      *reinterpret_cast<unsigned int*>(&wl[(n4 + j) * 136 + 2 * kp]) = pk;
    }
  }
}

// 8-step (K=128) MFMA tile, stride-16 frags.
DEVFN f32x16 mfma_tile(const unsigned short* __restrict__ xrow,
                       const unsigned short* __restrict__ wrow) {
  f32x16 acc;
  #pragma unroll
  for (int r = 0; r < 16; ++r) acc[r] = 0.f;
  #pragma unroll
  for (int kk = 0; kk < 8; ++kk) {
    const bf16x8 a = *reinterpret_cast<const bf16x8*>(xrow + kk * 16);
    const bf16x8 bb = *reinterpret_cast<const bf16x8*>(wrow + kk * 16);
    acc = __builtin_amdgcn_mfma_f32_32x32x16_bf16(a, bb, acc, 0, 0, 0);
  }
  return acc;
}

// C/D layout (verified m74/m101): col = lane&31, row = (r&3)+8*(r>>2)+4*(l>>5).
DEVFN void write_raw(float* __restrict__ raw, const f32x16 acc,
                     int tg, int cg, int lane) {
  const int n  = cg * 32 + (lane & 31);
  const int mb = tg * 32 + 4 * (lane >> 5);
  #pragma unroll
  for (int r = 0; r < 16; ++r) {
    const int mm = mb + (r & 3) + 8 * (r >> 2);
    raw[mm * 132 + n] = acc[r];
  }
}

// ---------------- Kernel 2: window gather + token_proj (bf16 MFMA) ----------
__global__ __launch_bounds__(512) void k_tok(const unsigned short* __restrict__ S3,
    const float* __restrict__ Wt, const float* __restrict__ bt,
    const float* __restrict__ gt, const float* __restrict__ bgt,
    float* __restrict__ tok) {
  __shared__ __align__(16) unsigned short xs_bf[64 * 136];
  __shared__ __align__(16) unsigned short wl[128 * 136];
  float* raw = reinterpret_cast<float*>(wl);

  const int tid = threadIdx.x;
  const int t0 = blockIdx.x * 64;
  const int s  = t0 >> 13;
  const int b  = (t0 >> 8) & 31;
  const int wyx = t0 & 255;

  const unsigned short* Sb = S3 + (size_t)b * 131072;
  #pragma unroll
  for (int p = 0; p < 2; ++p) {
    const int i = tid + p * 512;
    const int tt = i >> 4, c8 = (i & 15) * 8;
    const int idx = wyx + tt;
    const int wy = idx >> 4, wx = idx & 15;
    int ry0, ry1, c0, c1;
    if (s == 0) { ry0 = 2 * wy;     ry1 = 2 * wy + 1;        c0 = 2 * wx;     c1 = 2 * wx + 1; }
    else        { ry0 = 2 * wy + 1; ry1 = (2 * wy + 2) & 31; c0 = 2 * wx + 1; c1 = (2 * wx + 2) & 31; }
    const bf16x8 v00 = *reinterpret_cast<const bf16x8*>(Sb + ((size_t)(ry0 * 32 + c0) * 128 + c8));
    const bf16x8 v01 = *reinterpret_cast<const bf16x8*>(Sb + ((size_t)(ry0 * 32 + c1) * 128 + c8));
    const bf16x8 v10 = *reinterpret_cast<const bf16x8*>(Sb + ((size_t)(ry1 * 32 + c0) * 128 + c8));
    const bf16x8 v11 = *reinterpret_cast<const bf16x8*>(Sb + ((size_t)(ry1 * 32 + c1) * 128 + c8));
    bf16x8 pk;
    #pragma unroll
    for (int j = 0; j < 8; ++j) {
      const float sum = bf2f((unsigned short)v00[j]) + bf2f((unsigned short)v01[j]) +
                        bf2f((unsigned short)v10[j]) + bf2f((unsigned short)v11[j]);
      pk[j] = (short)f2bf(sum * (1.f / 36.f));
    }
    *reinterpret_cast<bf16x8*>(&xs_bf[tt * 136 + c8]) = pk;
  }
  stage_w_bf(wl, Wt, tid);
  __syncthreads();

  const int lane = tid & 63;
  const int w = tid >> 6;
  const int tg = w >> 2, cg = w & 3;
  const unsigned short* xrow = &xs_bf[(tg * 32 + (lane & 31)) * 136 + 8 * (lane >> 5)];
  const unsigned short* wrow = &wl[(cg * 32 + (lane & 31)) * 136 + 8 * (lane >> 5)];

  const f32x16 acc = mfma_tile(xrow, wrow);
  __syncthreads();
  write_raw(raw, acc, tg, cg, lane);
  __syncthreads();

  {
    const int tt = tid >> 3, cb = tid & 7;
    float v[16];
    float s2 = 0.f, q = 0.f;
    #pragma unroll
    for (int i = 0; i < 4; ++i) {
      const int col = 4 * cb + 32 * i;
      const float4 rv = *reinterpret_cast<const float4*>(&raw[tt * 132 + col]);
      const float4 bv = *reinterpret_cast<const float4*>(bt + col);
      v[4 * i + 0] = rv.x + bv.x; v[4 * i + 1] = rv.y + bv.y;
      v[4 * i + 2] = rv.z + bv.z; v[4 * i + 3] = rv.w + bv.w;
    }
    #pragma unroll
    for (int e = 0; e < 16; ++e) { s2 += v[e]; q += v[e] * v[e]; }
    s2 += __shfl_xor(s2, 1, 8); q += __shfl_xor(q, 1, 8);
    s2 += __shfl_xor(s2, 2, 8); q += __shfl_xor(q, 2, 8);
    s2 += __shfl_xor(s2, 4, 8); q += __shfl_xor(q, 4, 8);
    const float mean = s2 * (1.f / 128.f);
    const float var  = q * (1.f / 128.f) - mean * mean;
    const float inv  = rsqrtf(var + 1e-5f);
    #pragma unroll
    for (int i = 0; i < 4; ++i) {
      const int col = 4 * cb + 32 * i;
      const float4 gv = *reinterpret_cast<const float4*>(gt + col);
      const float4 ev = *reinterpret_cast<const float4*>(bgt + col);
      float4 ov;
      ov.x = gelu_fast((v[4 * i + 0] - mean) * inv * gv.x + ev.x);
      ov.y = gelu_fast((v[4 * i + 1] - mean) * inv * gv.y + ev.y);
      ov.z = gelu_fast((v[4 * i + 2] - mean) * inv * gv.z + ev.z);
      ov.w = gelu_fast((v[4 * i + 3] - mean) * inv * gv.w + ev.w);
      *reinterpret_cast<float4*>(tok + (size_t)(t0 + tt) * 128 + col) = ov;
    }
  }
}

// -------- Kernel 3: fuse + out_proj via bf16 MFMA + expand --------
// grid = 32*16 (b, m), 512 thr = 8 waves; wave (tg=w>>2, cg=w&3).
__global__ __launch_bounds__(512) void k_fuse_out(const float* __restrict__ tok,
    const float* __restrict__ Wf, const float* __restrict__ bfv,
    const float* __restrict__ gf, const float* __restrict__ bgf,
    const float* __restrict__ Wo, const float* __restrict__ bo,
    const float* __restrict__ go, const float* __restrict__ bgo,
    const float* __restrict__ mask, float* __restrict__ out) {
  __shared__ __align__(16) unsigned short xs_bf[64 * 136];   // 17408 B
  __shared__ __align__(16) unsigned short wl[128 * 136];     // 34816 B
  float* raw = reinterpret_cast<float*>(wl);                 // [64][132] f32

  const int tid = threadIdx.x;
  const int b = blockIdx.x >> 4;
  const int m = blockIdx.x & 15;
  const int lane = tid & 63;
  const int w = tid >> 6;
  const int tg = w >> 2, cg = w & 3;

  const float* tokR = tok + (size_t)b * 32768 + (size_t)m * 2048;
  const float* tokS = tok + 1048576 + (size_t)b * 32768;

  // Phase 0: gather reg+sh -> bf16 xs ; stage Wf transposed-bf16.
  #pragma unroll
  for (int p = 0; p < 2; ++p) {
    const int i = tid + p * 512;
    const int t = i >> 4, c8 = (i & 15) * 8;
    const int gx = t & 31, gy = 2 * m + (t >> 5);
    const int wx  = gx >> 1;
    const int wxs = ((gx + 31) & 31) >> 1;
    const int wys = ((gy + 31) & 31) >> 1;
    const float* pr = tokR + (size_t)wx * 128 + c8;
    const float* ps = tokS + (size_t)(wys * 16 + wxs) * 128 + c8;
    bf16x8 pk;
    #pragma unroll
    for (int j = 0; j < 8; ++j)
      pk[j] = (short)f2bf(pr[j] + ps[j]);
    *reinterpret_cast<bf16x8*>(&xs_bf[t * 136 + c8]) = pk;
  }
  stage_w_bf(wl, Wf, tid);
  __syncthreads();

  const unsigned short* xrow = &xs_bf[(tg * 32 + (lane & 31)) * 136 + 8 * (lane >> 5)];
  const unsigned short* wrow = &wl[(cg * 32 + (lane & 31)) * 136 + 8 * (lane >> 5)];

  // Phase 1: fuse GEMM.
  const f32x16 acc1 = mfma_tile(xrow, wrow);
  __syncthreads();                        // all wl reads done before raw write
  write_raw(raw, acc1, tg, cg, lane);
  __syncthreads();

  // Phase 2: LN+GELU(ctx) -> bf16 back into xs_bf. 8 threads/token.
  {
    const int tt = tid >> 3, cb = tid & 7;
    float v[16];
    float s = 0.f, q = 0.f;
    #pragma unroll
    for (int i = 0; i < 4; ++i) {
      const int col = 4 * cb + 32 * i;
      const float4 rv = *reinterpret_cast<const float4*>(&raw[tt * 132 + col]);
      const float4 bv = *reinterpret_cast<const float4*>(bfv + col);
      v[4 * i + 0] = rv.x + bv.x; v[4 * i + 1] = rv.y + bv.y;
      v[4 * i + 2] = rv.z + bv.z; v[4 * i + 3] = rv.w + bv.w;
    }
    #pragma unroll
    for (int e = 0; e < 16; ++e) { s += v[e]; q += v[e] * v[e]; }
    s += __shfl_xor(s, 1, 8); q += __shfl_xor(q, 1, 8);
    s += __shfl_xor(s, 2, 8); q += __shfl_xor(q, 2, 8);
    s += __shfl_xor(s, 4, 8); q += __shfl_xor(q, 4, 8);
    const float mean = s * (1.f / 128.f);
    const float var  = q * (1.f / 128.f) - mean * mean;
    const float inv  = rsqrtf(var + 1e-5f);
    // NOTE: no barrier needed here — each thread's raw reads complete before
    // it reaches the outer barrier below; xs writes don't alias raw.
    #pragma unroll
    for (int i = 0; i < 4; ++i) {
      const int col = 4 * cb + 32 * i;
      const float4 gv = *reinterpret_cast<const float4*>(gf + col);
      const float4 ev = *reinterpret_cast<const float4*>(bgf + col);
      short4 pk;
      pk.x = (short)f2bf(gelu_fast((v[4 * i + 0] - mean) * inv * gv.x + ev.x));
      pk.y = (short)f2bf(gelu_fast((v[4 * i + 1] - mean) * inv * gv.y + ev.y));
      pk.z = (short)f2bf(gelu_fast((v[4 * i + 2] - mean) * inv * gv.z + ev.z));
      pk.w = (short)f2bf(gelu_fast((v[4 * i + 3] - mean) * inv * gv.w + ev.w));
      *reinterpret_cast<short4*>(&xs_bf[tt * 136 + col]) = pk;
    }
  }
  __syncthreads();                        // ctx complete; raw reads done
  stage_w_bf(wl, Wo, tid);
  __syncthreads();

  // Phase 3: out_proj GEMM.
  const f32x16 acc2 = mfma_tile(xrow, wrow);
  __syncthreads();
  write_raw(raw, acc2, tg, cg, lane);
  __syncthreads();

  // Phase 4: LN+GELU(out) + mask + 3x3 expand stores.
  {
    const int tt = tid >> 3, cb = tid & 7;
    float v[16];
    float s = 0.f, q = 0.f;
    #pragma unroll
    for (int i = 0; i < 4; ++i) {
      const int col = 4 * cb + 32 * i;
      const float4 rv = *reinterpret_cast<const float4*>(&raw[tt * 132 + col]);
      const float4 bv = *reinterpret_cast<const float4*>(bo + col);
      v[4 * i + 0] = rv.x + bv.x; v[4 * i + 1] = rv.y + bv.y;
      v[4 * i + 2] = rv.z + bv.z; v[4 * i + 3] = rv.w + bv.w;
    }
    #pragma unroll
    for (int e = 0; e < 16; ++e) { s += v[e]; q += v[e] * v[e]; }
    s += __shfl_xor(s, 1, 8); q += __shfl_xor(q, 1, 8);
    s += __shfl_xor(s, 2, 8); q += __shfl_xor(q, 2, 8);
    s += __shfl_xor(s, 4, 8); q += __shfl_xor(q, 4, 8);
    const float mean = s * (1.f / 128.f);
    const float var  = q * (1.f / 128.f) - mean * mean;
    const float inv  = rsqrtf(var + 1e-5f);
    #pragma unroll
    for (int i = 0; i < 4; ++i) {
      const int col = 4 * cb + 32 * i;
      const float4 gv = *reinterpret_cast<const float4*>(go + col);
      const float4 ev = *reinterpret_cast<const float4*>(bgo + col);
      v[4 * i + 0] = gelu_fast((v[4 * i + 0] - mean) * inv * gv.x + ev.x);
      v[4 * i + 1] = gelu_fast((v[4 * i + 1] - mean) * inv * gv.y + ev.y);
      v[4 * i + 2] = gelu_fast((v[4 * i + 2] - mean) * inv * gv.z + ev.z);
      v[4 * i + 3] = gelu_fast((v[4 * i + 3] - mean) * inv * gv.w + ev.w);
    }
    const int gx = tt & 31, gy = 2 * m + (tt >> 5);
    #pragma unroll
    for (int py = 0; py < 3; ++py) {
      const int y = 3 * gy + py;
      #pragma unroll
      for (int px = 0; px < 3; ++px) {
        const int x = 3 * gx + px;
        const size_t pix = (size_t)b * 9216 + (size_t)y * 96 + x;
        const float mv = mask[pix];
        #pragma unroll
        for (int i = 0; i < 4; ++i) {
          const int col = 4 * cb + 32 * i;
          *reinterpret_cast<float4*>(out + pix * 128 + col) =
              make_float4(v[4 * i + 0] * mv, v[4 * i + 1] * mv,
                          v[4 * i + 2] * mv, v[4 * i + 3] * mv);
        }
      }
    }
  }
}

extern "C" void kernel_launch(void* const* d_in, const int* in_sizes, int n_in,
                              void* d_out, int out_size, void* d_ws, size_t ws_size,
                              hipStream_t stream) {
  (void)in_sizes; (void)n_in; (void)out_size; (void)ws_size;
  const float* h    = (const float*)d_in[0];
  const float* mask = (const float*)d_in[1];
  const float* Wt   = (const float*)d_in[2];
  const float* bt   = (const float*)d_in[3];
  const float* gt   = (const float*)d_in[4];
  const float* bgt  = (const float*)d_in[5];
  const float* Wf   = (const float*)d_in[6];
  const float* bfv  = (const float*)d_in[7];
  const float* gf   = (const float*)d_in[8];
  const float* bgf  = (const float*)d_in[9];
  const float* Wo   = (const float*)d_in[10];
  const float* bo   = (const float*)d_in[11];
  const float* go   = (const float*)d_in[12];
  const float* bgo  = (const float*)d_in[13];

  unsigned short* S3 = (unsigned short*)d_ws;                    // 8 MB
  float* tok = (float*)((char*)d_ws + (size_t)8 * 1024 * 1024);  // 8 MB
  float* out = (float*)d_out;

  hipLaunchKernelGGL(k_tile3, dim3(1024), dim3(512), 0, stream, h, S3);
  hipLaunchKernelGGL(k_tok, dim3(256), dim3(512), 0, stream,
                     S3, Wt, bt, gt, bgt, tok);
  hipLaunchKernelGGL(k_fuse_out, dim3(512), dim3(512), 0, stream,
                     tok, Wf, bfv, gf, bgf, Wo, bo, go, bgo, mask, out);
}

// Round 16
// 76.351 us; speedup vs baseline: 1.3494x; 1.1547x over previous
//
#include <hip/hip_runtime.h>
#include <hip/hip_bf16.h>

// B=32, H=W=96, D=128, WS=6, SS=3.
// Pipeline (round-11/14 proven structure; surgical cuts only):
//  k_tile3   : h (151 MB, read ONCE) -> 3x3-tile sums S3 bf16 (8 MB ws)
//  k_tok     : S3 -> window means -> token_proj (bf16 MFMA) -> tok BF16 (4 MB ws)
//  k_fuse_out: tok -> fuse + out_proj (bf16 MFMA) -> 3x3 expand -> out f32
// Changes vs round 14: (1) all paired f32->bf16 packs via HW v_cvt_pk_bf16_f32
// (RNE; 1 instr vs ~7 manual); (2) tok stored bf16 (halves tok write + gather
// read; +<=1 bf16 ulp double-rounding, margin 3x); (3) nontemporal stores for
// S3/tok/out via clang ext_vector types (HIP_vector_type rejected by builtin).
// S3 b-stride = 131072 elems (32*32*128). tok b-stride 32768, set-stride 1048576.

#define DEVFN static __device__ __forceinline__

typedef __attribute__((ext_vector_type(8))) short bf16x8;
typedef __attribute__((ext_vector_type(16))) float f32x16;
typedef __attribute__((ext_vector_type(2))) unsigned int uintx2;
typedef __attribute__((ext_vector_type(4))) float floatx4;

DEVFN float gelu_fast(float x) {
  // tanh-form GELU == x * sigmoid(2*0.7978845608*(x + 0.044715 x^3))
  const float u = 1.5957691216057308f * (x + 0.044715f * x * x * x);
  return x / (1.0f + __expf(-u));
}

DEVFN unsigned int cvt_pk_bf16(float lo, float hi) {  // HW RNE pack
  unsigned int r;
  asm("v_cvt_pk_bf16_f32 %0, %1, %2" : "=v"(r) : "v"(lo), "v"(hi));
  return r;
}

DEVFN float bf2f(unsigned short u) {
  return __uint_as_float((unsigned int)u << 16);
}

DEVFN void add4(float4& a, const float4 v) {
  a.x += v.x; a.y += v.y; a.z += v.z; a.w += v.w;
}
DEVFN void fma4(float4& a, const float4 v, float m) {
  a.x = fmaf(v.x, m, a.x); a.y = fmaf(v.y, m, a.y);
  a.z = fmaf(v.z, m, a.z); a.w = fmaf(v.w, m, a.w);
}

// ---------------- Kernel 1: 3x3-tile sums, bf16 output ----------------
__global__ __launch_bounds__(512) void k_tile3(const float* __restrict__ h,
                                               unsigned short* __restrict__ S3) {
  const int b  = blockIdx.x >> 5;
  const int ry = blockIdx.x & 31;
  const int w    = threadIdx.x >> 6;
  const int lane = threadIdx.x & 63;
  const int half = lane >> 5;
  const int ch4  = (lane & 31) << 2;
  const float mlo = half ? 0.f : 1.f;
  const float mhi = 1.f - mlo;

  float4 acc[4];
  #pragma unroll
  for (int t = 0; t < 4; ++t) acc[t] = make_float4(0.f, 0.f, 0.f, 0.f);

  #pragma unroll
  for (int yy = 0; yy < 3; ++yy) {
    const float* rp =
        h + ((size_t)(b * 9216 + (3 * ry + yy) * 96 + 12 * w + half) * 128 + ch4);
    #pragma unroll
    for (int j = 0; j < 6; ++j) {        // col = 12w + 2j + half
      const float4 v = *reinterpret_cast<const float4*>(rp + j * 256);
      if (j == 0)      add4(acc[0], v);
      else if (j == 2) add4(acc[1], v);
      else if (j == 3) add4(acc[2], v);
      else if (j == 5) add4(acc[3], v);
      else if (j == 1) { fma4(acc[0], v, mlo); fma4(acc[1], v, mhi); }
      else             { fma4(acc[2], v, mlo); fma4(acc[3], v, mhi); }
    }
  }

  #pragma unroll
  for (int t = 0; t < 4; ++t) {
    float4 s = acc[t];
    s.x += __shfl_xor(s.x, 32, 64);
    s.y += __shfl_xor(s.y, 32, 64);
    s.z += __shfl_xor(s.z, 32, 64);
    s.w += __shfl_xor(s.w, 32, 64);
    if (half == 0) {
      uintx2 pk;
      pk.x = cvt_pk_bf16(s.x, s.y);
      pk.y = cvt_pk_bf16(s.z, s.w);
      __builtin_nontemporal_store(pk, reinterpret_cast<uintx2*>(
          &S3[((size_t)(b * 32 + ry) * 32 + 4 * w + t) * 128 + ch4]));
    }
  }
}

// ---------------- MFMA helpers ----------------
// Stage W (f32 global, [k][n]) -> transposed bf16 LDS Wl[n][k], rows padded
// to 136 elems for conflict-free b128 frag reads.
DEVFN void stage_w_bf(unsigned short* __restrict__ wl,
                      const float* __restrict__ W, int tid) {
  #pragma unroll
  for (int p = 0; p < 4; ++p) {
    const int i = tid + p * 512;
    const int kp = i >> 5;
    const int n4 = (i & 31) * 4;
    const float4 r0 = *reinterpret_cast<const float4*>(W + (size_t)(2 * kp) * 128 + n4);
    const float4 r1 = *reinterpret_cast<const float4*>(W + (size_t)(2 * kp + 1) * 128 + n4);
    const float a0[4] = {r0.x, r0.y, r0.z, r0.w};
    const float a1[4] = {r1.x, r1.y, r1.z, r1.w};
    #pragma unroll
    for (int j = 0; j < 4; ++j) {
      *reinterpret_cast<unsigned int*>(&wl[(n4 + j) * 136 + 2 * kp]) =
          cvt_pk_bf16(a0[j], a1[j]);
    }
  }
}

// 8-step (K=128) MFMA tile, stride-16 frags.
DEVFN f32x16 mfma_tile(const unsigned short* __restrict__ xrow,
                       const unsigned short* __restrict__ wrow) {
  f32x16 acc;
  #pragma unroll
  for (int r = 0; r < 16; ++r) acc[r] = 0.f;
  #pragma unroll
  for (int kk = 0; kk < 8; ++kk) {
    const bf16x8 a = *reinterpret_cast<const bf16x8*>(xrow + kk * 16);
    const bf16x8 bb = *reinterpret_cast<const bf16x8*>(wrow + kk * 16);
    acc = __builtin_amdgcn_mfma_f32_32x32x16_bf16(a, bb, acc, 0, 0, 0);
  }
  return acc;
}

// C/D layout (verified m74/m101): col = lane&31, row = (r&3)+8*(r>>2)+4*(l>>5).
DEVFN void write_raw(float* __restrict__ raw, const f32x16 acc,
                     int tg, int cg, int lane) {
  const int n  = cg * 32 + (lane & 31);
  const int mb = tg * 32 + 4 * (lane >> 5);
  #pragma unroll
  for (int r = 0; r < 16; ++r) {
    const int mm = mb + (r & 3) + 8 * (r >> 2);
    raw[mm * 132 + n] = acc[r];
  }
}

// ---------------- Kernel 2: window gather + token_proj (bf16 MFMA) ----------
// tok output now BF16 (u16), same element-indexed layout as before.
__global__ __launch_bounds__(512) void k_tok(const unsigned short* __restrict__ S3,
    const float* __restrict__ Wt, const float* __restrict__ bt,
    const float* __restrict__ gt, const float* __restrict__ bgt,
    unsigned short* __restrict__ tok) {
  __shared__ __align__(16) unsigned short xs_bf[64 * 136];
  __shared__ __align__(16) unsigned short wl[128 * 136];
  float* raw = reinterpret_cast<float*>(wl);

  const int tid = threadIdx.x;
  const int t0 = blockIdx.x * 64;
  const int s  = t0 >> 13;
  const int b  = (t0 >> 8) & 31;
  const int wyx = t0 & 255;

  const unsigned short* Sb = S3 + (size_t)b * 131072;
  #pragma unroll
  for (int p = 0; p < 2; ++p) {
    const int i = tid + p * 512;
    const int tt = i >> 4, c8 = (i & 15) * 8;
    const int idx = wyx + tt;
    const int wy = idx >> 4, wx = idx & 15;
    int ry0, ry1, c0, c1;
    if (s == 0) { ry0 = 2 * wy;     ry1 = 2 * wy + 1;        c0 = 2 * wx;     c1 = 2 * wx + 1; }
    else        { ry0 = 2 * wy + 1; ry1 = (2 * wy + 2) & 31; c0 = 2 * wx + 1; c1 = (2 * wx + 2) & 31; }
    const bf16x8 v00 = *reinterpret_cast<const bf16x8*>(Sb + ((size_t)(ry0 * 32 + c0) * 128 + c8));
    const bf16x8 v01 = *reinterpret_cast<const bf16x8*>(Sb + ((size_t)(ry0 * 32 + c1) * 128 + c8));
    const bf16x8 v10 = *reinterpret_cast<const bf16x8*>(Sb + ((size_t)(ry1 * 32 + c0) * 128 + c8));
    const bf16x8 v11 = *reinterpret_cast<const bf16x8*>(Sb + ((size_t)(ry1 * 32 + c1) * 128 + c8));
    float sv[8];
    #pragma unroll
    for (int j = 0; j < 8; ++j) {
      sv[j] = (bf2f((unsigned short)v00[j]) + bf2f((unsigned short)v01[j]) +
               bf2f((unsigned short)v10[j]) + bf2f((unsigned short)v11[j])) * (1.f / 36.f);
    }
    unsigned int* dst = reinterpret_cast<unsigned int*>(&xs_bf[tt * 136 + c8]);
    #pragma unroll
    for (int j = 0; j < 4; ++j)
      dst[j] = cvt_pk_bf16(sv[2 * j], sv[2 * j + 1]);
  }
  stage_w_bf(wl, Wt, tid);
  __syncthreads();

  const int lane = tid & 63;
  const int w = tid >> 6;
  const int tg = w >> 2, cg = w & 3;
  const unsigned short* xrow = &xs_bf[(tg * 32 + (lane & 31)) * 136 + 8 * (lane >> 5)];
  const unsigned short* wrow = &wl[(cg * 32 + (lane & 31)) * 136 + 8 * (lane >> 5)];

  const f32x16 acc = mfma_tile(xrow, wrow);
  __syncthreads();
  write_raw(raw, acc, tg, cg, lane);
  __syncthreads();

  {
    const int tt = tid >> 3, cb = tid & 7;
    float v[16];
    float s2 = 0.f, q = 0.f;
    #pragma unroll
    for (int i = 0; i < 4; ++i) {
      const int col = 4 * cb + 32 * i;
      const float4 rv = *reinterpret_cast<const float4*>(&raw[tt * 132 + col]);
      const float4 bv = *reinterpret_cast<const float4*>(bt + col);
      v[4 * i + 0] = rv.x + bv.x; v[4 * i + 1] = rv.y + bv.y;
      v[4 * i + 2] = rv.z + bv.z; v[4 * i + 3] = rv.w + bv.w;
    }
    #pragma unroll
    for (int e = 0; e < 16; ++e) { s2 += v[e]; q += v[e] * v[e]; }
    s2 += __shfl_xor(s2, 1, 8); q += __shfl_xor(q, 1, 8);
    s2 += __shfl_xor(s2, 2, 8); q += __shfl_xor(q, 2, 8);
    s2 += __shfl_xor(s2, 4, 8); q += __shfl_xor(q, 4, 8);
    const float mean = s2 * (1.f / 128.f);
    const float var  = q * (1.f / 128.f) - mean * mean;
    const float inv  = rsqrtf(var + 1e-5f);
    #pragma unroll
    for (int i = 0; i < 4; ++i) {
      const int col = 4 * cb + 32 * i;
      const float4 gv = *reinterpret_cast<const float4*>(gt + col);
      const float4 ev = *reinterpret_cast<const float4*>(bgt + col);
      const float o0 = gelu_fast((v[4 * i + 0] - mean) * inv * gv.x + ev.x);
      const float o1 = gelu_fast((v[4 * i + 1] - mean) * inv * gv.y + ev.y);
      const float o2 = gelu_fast((v[4 * i + 2] - mean) * inv * gv.z + ev.z);
      const float o3 = gelu_fast((v[4 * i + 3] - mean) * inv * gv.w + ev.w);
      uintx2 pk;
      pk.x = cvt_pk_bf16(o0, o1);
      pk.y = cvt_pk_bf16(o2, o3);
      __builtin_nontemporal_store(pk, reinterpret_cast<uintx2*>(
          tok + (size_t)(t0 + tt) * 128 + col));
    }
  }
}

// -------- Kernel 3: fuse + out_proj via bf16 MFMA + expand --------
// grid = 32*16 (b, m), 512 thr = 8 waves; wave (tg=w>>2, cg=w&3).
__global__ __launch_bounds__(512) void k_fuse_out(const unsigned short* __restrict__ tok,
    const float* __restrict__ Wf, const float* __restrict__ bfv,
    const float* __restrict__ gf, const float* __restrict__ bgf,
    const float* __restrict__ Wo, const float* __restrict__ bo,
    const float* __restrict__ go, const float* __restrict__ bgo,
    const float* __restrict__ mask, float* __restrict__ out) {
  __shared__ __align__(16) unsigned short xs_bf[64 * 136];   // 17408 B
  __shared__ __align__(16) unsigned short wl[128 * 136];     // 34816 B
  float* raw = reinterpret_cast<float*>(wl);                 // [64][132] f32

  const int tid = threadIdx.x;
  const int b = blockIdx.x >> 4;
  const int m = blockIdx.x & 15;
  const int lane = tid & 63;
  const int w = tid >> 6;
  const int tg = w >> 2, cg = w & 3;

  const unsigned short* tokR = tok + (size_t)b * 32768 + (size_t)m * 2048;
  const unsigned short* tokS = tok + 1048576 + (size_t)b * 32768;

  // Phase 0: gather reg+sh (bf16) -> bf16 xs ; stage Wf transposed-bf16.
  #pragma unroll
  for (int p = 0; p < 2; ++p) {
    const int i = tid + p * 512;
    const int t = i >> 4, c8 = (i & 15) * 8;
    const int gx = t & 31, gy = 2 * m + (t >> 5);
    const int wx  = gx >> 1;
    const int wxs = ((gx + 31) & 31) >> 1;
    const int wys = ((gy + 31) & 31) >> 1;
    const bf16x8 pr = *reinterpret_cast<const bf16x8*>(tokR + (size_t)wx * 128 + c8);
    const bf16x8 ps = *reinterpret_cast<const bf16x8*>(tokS + (size_t)(wys * 16 + wxs) * 128 + c8);
    float sv[8];
    #pragma unroll
    for (int j = 0; j < 8; ++j)
      sv[j] = bf2f((unsigned short)pr[j]) + bf2f((unsigned short)ps[j]);
    unsigned int* dst = reinterpret_cast<unsigned int*>(&xs_bf[t * 136 + c8]);
    #pragma unroll
    for (int j = 0; j < 4; ++j)
      dst[j] = cvt_pk_bf16(sv[2 * j], sv[2 * j + 1]);
  }
  stage_w_bf(wl, Wf, tid);
  __syncthreads();

  const unsigned short* xrow = &xs_bf[(tg * 32 + (lane & 31)) * 136 + 8 * (lane >> 5)];
  const unsigned short* wrow = &wl[(cg * 32 + (lane & 31)) * 136 + 8 * (lane >> 5)];

  // Phase 1: fuse GEMM.
  const f32x16 acc1 = mfma_tile(xrow, wrow);
  __syncthreads();                        // all wl reads done before raw write
  write_raw(raw, acc1, tg, cg, lane);
  __syncthreads();

  // Phase 2: LN+GELU(ctx) -> bf16 back into xs_bf. 8 threads/token.
  {
    const int tt = tid >> 3, cb = tid & 7;
    float v[16];
    float s = 0.f, q = 0.f;
    #pragma unroll
    for (int i = 0; i < 4; ++i) {
      const int col = 4 * cb + 32 * i;
      const float4 rv = *reinterpret_cast<const float4*>(&raw[tt * 132 + col]);
      const float4 bv = *reinterpret_cast<const float4*>(bfv + col);
      v[4 * i + 0] = rv.x + bv.x; v[4 * i + 1] = rv.y + bv.y;
      v[4 * i + 2] = rv.z + bv.z; v[4 * i + 3] = rv.w + bv.w;
    }
    #pragma unroll
    for (int e = 0; e < 16; ++e) { s += v[e]; q += v[e] * v[e]; }
    s += __shfl_xor(s, 1, 8); q += __shfl_xor(q, 1, 8);
    s += __shfl_xor(s, 2, 8); q += __shfl_xor(q, 2, 8);
    s += __shfl_xor(s, 4, 8); q += __shfl_xor(q, 4, 8);
    const float mean = s * (1.f / 128.f);
    const float var  = q * (1.f / 128.f) - mean * mean;
    const float inv  = rsqrtf(var + 1e-5f);
    #pragma unroll
    for (int i = 0; i < 4; ++i) {
      const int col = 4 * cb + 32 * i;
      const float4 gv = *reinterpret_cast<const float4*>(gf + col);
      const float4 ev = *reinterpret_cast<const float4*>(bgf + col);
      const float o0 = gelu_fast((v[4 * i + 0] - mean) * inv * gv.x + ev.x);
      const float o1 = gelu_fast((v[4 * i + 1] - mean) * inv * gv.y + ev.y);
      const float o2 = gelu_fast((v[4 * i + 2] - mean) * inv * gv.z + ev.z);
      const float o3 = gelu_fast((v[4 * i + 3] - mean) * inv * gv.w + ev.w);
      uintx2 pk;
      pk.x = cvt_pk_bf16(o0, o1);
      pk.y = cvt_pk_bf16(o2, o3);
      *reinterpret_cast<uintx2*>(&xs_bf[tt * 136 + col]) = pk;
    }
  }
  __syncthreads();                        // ctx complete; raw reads done
  stage_w_bf(wl, Wo, tid);
  __syncthreads();

  // Phase 3: out_proj GEMM.
  const f32x16 acc2 = mfma_tile(xrow, wrow);
  __syncthreads();
  write_raw(raw, acc2, tg, cg, lane);
  __syncthreads();

  // Phase 4: LN+GELU(out) + mask + 3x3 expand nontemporal stores.
  {
    const int tt = tid >> 3, cb = tid & 7;
    float v[16];
    float s = 0.f, q = 0.f;
    #pragma unroll
    for (int i = 0; i < 4; ++i) {
      const int col = 4 * cb + 32 * i;
      const float4 rv = *reinterpret_cast<const float4*>(&raw[tt * 132 + col]);
      const float4 bv = *reinterpret_cast<const float4*>(bo + col);
      v[4 * i + 0] = rv.x + bv.x; v[4 * i + 1] = rv.y + bv.y;
      v[4 * i + 2] = rv.z + bv.z; v[4 * i + 3] = rv.w + bv.w;
    }
    #pragma unroll
    for (int e = 0; e < 16; ++e) { s += v[e]; q += v[e] * v[e]; }
    s += __shfl_xor(s, 1, 8); q += __shfl_xor(q, 1, 8);
    s += __shfl_xor(s, 2, 8); q += __shfl_xor(q, 2, 8);
    s += __shfl_xor(s, 4, 8); q += __shfl_xor(q, 4, 8);
    const float mean = s * (1.f / 128.f);
    const float var  = q * (1.f / 128.f) - mean * mean;
    const float inv  = rsqrtf(var + 1e-5f);
    #pragma unroll
    for (int i = 0; i < 4; ++i) {
      const int col = 4 * cb + 32 * i;
      const float4 gv = *reinterpret_cast<const float4*>(go + col);
      const float4 ev = *reinterpret_cast<const float4*>(bgo + col);
      v[4 * i + 0] = gelu_fast((v[4 * i + 0] - mean) * inv * gv.x + ev.x);
      v[4 * i + 1] = gelu_fast((v[4 * i + 1] - mean) * inv * gv.y + ev.y);
      v[4 * i + 2] = gelu_fast((v[4 * i + 2] - mean) * inv * gv.z + ev.z);
      v[4 * i + 3] = gelu_fast((v[4 * i + 3] - mean) * inv * gv.w + ev.w);
    }
    const int gx = tt & 31, gy = 2 * m + (tt >> 5);
    #pragma unroll
    for (int py = 0; py < 3; ++py) {
      const int y = 3 * gy + py;
      #pragma unroll
      for (int px = 0; px < 3; ++px) {
        const int x = 3 * gx + px;
        const size_t pix = (size_t)b * 9216 + (size_t)y * 96 + x;
        const float mv = mask[pix];
        #pragma unroll
        for (int i = 0; i < 4; ++i) {
          const int col = 4 * cb + 32 * i;
          floatx4 ov;
          ov.x = v[4 * i + 0] * mv; ov.y = v[4 * i + 1] * mv;
          ov.z = v[4 * i + 2] * mv; ov.w = v[4 * i + 3] * mv;
          __builtin_nontemporal_store(ov,
              reinterpret_cast<floatx4*>(out + pix * 128 + col));
        }
      }
    }
  }
}

extern "C" void kernel_launch(void* const* d_in, const int* in_sizes, int n_in,
                              void* d_out, int out_size, void* d_ws, size_t ws_size,
                              hipStream_t stream) {
  (void)in_sizes; (void)n_in; (void)out_size; (void)ws_size;
  const float* h    = (const float*)d_in[0];
  const float* mask = (const float*)d_in[1];
  const float* Wt   = (const float*)d_in[2];
  const float* bt   = (const float*)d_in[3];
  const float* gt   = (const float*)d_in[4];
  const float* bgt  = (const float*)d_in[5];
  const float* Wf   = (const float*)d_in[6];
  const float* bfv  = (const float*)d_in[7];
  const float* gf   = (const float*)d_in[8];
  const float* bgf  = (const float*)d_in[9];
  const float* Wo   = (const float*)d_in[10];
  const float* bo   = (const float*)d_in[11];
  const float* go   = (const float*)d_in[12];
  const float* bgo  = (const float*)d_in[13];

  unsigned short* S3  = (unsigned short*)d_ws;                          // 8 MB
  unsigned short* tok = (unsigned short*)((char*)d_ws + (size_t)8 * 1024 * 1024);  // 4 MB
  float* out = (float*)d_out;

  hipLaunchKernelGGL(k_tile3, dim3(1024), dim3(512), 0, stream, h, S3);
  hipLaunchKernelGGL(k_tok, dim3(256), dim3(512), 0, stream,
                     S3, Wt, bt, gt, bgt, tok);
  hipLaunchKernelGGL(k_fuse_out, dim3(512), dim3(512), 0, stream,
                     tok, Wf, bfv, gf, bgf, Wo, bo, go, bgo, mask, out);
}

// Round 17
// 76.311 us; speedup vs baseline: 1.3501x; 1.0005x over previous
//
#include <hip/hip_runtime.h>
#include <hip/hip_bf16.h>

// B=32, H=W=96, D=128, WS=6, SS=3.
// Pipeline (proven structure; surgical cuts only):
//  k_tile3   : h (151 MB, read ONCE, nontemporal) -> S3 bf16 (8 MB ws);
//              blocks 1024..1026 also pre-convert Wt/Wf/Wo -> bf16 transposed
//              LDS-byte-images (34816 B each) at ws+12MB (zero extra launch).
//  k_tok     : S3 -> window means -> token_proj (bf16 MFMA) -> tok bf16 (4 MB ws)
//  k_fuse_out: tok -> fuse + out_proj (bf16 MFMA) -> 3x3 expand -> out f32
// W staging in tok/fuse_out = pure uint4 copy of the image (half bytes, 0 cvt).
// GELU uses HW rcp (~1e-7 rel; invisible at bf16). Everything else = round 16.
// S3 b-stride 131072 elems; tok b-stride 32768, set-stride 1048576.

#define DEVFN static __device__ __forceinline__

typedef __attribute__((ext_vector_type(8))) short bf16x8;
typedef __attribute__((ext_vector_type(16))) float f32x16;
typedef __attribute__((ext_vector_type(2))) unsigned int uintx2;
typedef __attribute__((ext_vector_type(4))) float floatx4;

DEVFN float gelu_fast(float x) {
  // tanh-form GELU == x * sigmoid(2*0.7978845608*(x + 0.044715 x^3))
  const float u = 1.5957691216057308f * (x + 0.044715f * x * x * x);
  return x * __builtin_amdgcn_rcpf(1.0f + __expf(-u));
}

DEVFN unsigned int cvt_pk_bf16(float lo, float hi) {  // HW RNE pack
  unsigned int r;
  asm("v_cvt_pk_bf16_f32 %0, %1, %2" : "=v"(r) : "v"(lo), "v"(hi));
  return r;
}

DEVFN float bf2f(unsigned short u) {
  return __uint_as_float((unsigned int)u << 16);
}

DEVFN void add4(float4& a, const float4 v) {
  a.x += v.x; a.y += v.y; a.z += v.z; a.w += v.w;
}
DEVFN void fma4(float4& a, const float4 v, float m) {
  a.x = fmaf(v.x, m, a.x); a.y = fmaf(v.y, m, a.y);
  a.z = fmaf(v.z, m, a.z); a.w = fmaf(v.w, m, a.w);
}

// ---------------- Kernel 1: 3x3-tile sums + W image prep ----------------
// grid = 32*32 + 3. Blocks <1024: tile sums (rows 3ry..3ry+2, no halo).
// Blocks 1024..1026: convert Wt/Wf/Wo (f32 [k][n]) -> bf16 image [n][136]u16
// (k-major rows, 8-elem pad; exact byte image of the LDS wl buffer).
__global__ __launch_bounds__(512) void k_tile3(const float* __restrict__ h,
    const float* __restrict__ Wt, const float* __restrict__ Wf,
    const float* __restrict__ Wo,
    unsigned short* __restrict__ S3, unsigned int* __restrict__ imgs) {
  const int tid = threadIdx.x;
  if (blockIdx.x >= 1024) {
    const int which = blockIdx.x - 1024;
    const float* W = (which == 0) ? Wt : (which == 1) ? Wf : Wo;
    unsigned int* img = imgs + (size_t)which * 8704;
    #pragma unroll
    for (int p = 0; p < 4; ++p) {
      const int i = tid + p * 512;          // 0..2047: kpair x n4-chunk
      const int kp = i >> 5;                // k pair 0..63
      const int n4 = (i & 31) * 4;
      const float4 r0 = *reinterpret_cast<const float4*>(W + (size_t)(2 * kp) * 128 + n4);
      const float4 r1 = *reinterpret_cast<const float4*>(W + (size_t)(2 * kp + 1) * 128 + n4);
      const float a0[4] = {r0.x, r0.y, r0.z, r0.w};
      const float a1[4] = {r1.x, r1.y, r1.z, r1.w};
      #pragma unroll
      for (int j = 0; j < 4; ++j)
        img[(n4 + j) * 68 + kp] = cvt_pk_bf16(a0[j], a1[j]);
    }
    return;
  }

  const int b  = blockIdx.x >> 5;
  const int ry = blockIdx.x & 31;
  const int w    = tid >> 6;
  const int lane = tid & 63;
  const int half = lane >> 5;
  const int ch4  = (lane & 31) << 2;
  const float mlo = half ? 0.f : 1.f;
  const float mhi = 1.f - mlo;

  float4 acc[4];
  #pragma unroll
  for (int t = 0; t < 4; ++t) acc[t] = make_float4(0.f, 0.f, 0.f, 0.f);

  #pragma unroll
  for (int yy = 0; yy < 3; ++yy) {
    const float* rp =
        h + ((size_t)(b * 9216 + (3 * ry + yy) * 96 + 12 * w + half) * 128 + ch4);
    #pragma unroll
    for (int j = 0; j < 6; ++j) {        // col = 12w + 2j + half
      const floatx4 vv = __builtin_nontemporal_load(
          reinterpret_cast<const floatx4*>(rp + j * 256));
      const float4 v = make_float4(vv.x, vv.y, vv.z, vv.w);
      if (j == 0)      add4(acc[0], v);
      else if (j == 2) add4(acc[1], v);
      else if (j == 3) add4(acc[2], v);
      else if (j == 5) add4(acc[3], v);
      else if (j == 1) { fma4(acc[0], v, mlo); fma4(acc[1], v, mhi); }
      else             { fma4(acc[2], v, mlo); fma4(acc[3], v, mhi); }
    }
  }

  #pragma unroll
  for (int t = 0; t < 4; ++t) {
    float4 s = acc[t];
    s.x += __shfl_xor(s.x, 32, 64);
    s.y += __shfl_xor(s.y, 32, 64);
    s.z += __shfl_xor(s.z, 32, 64);
    s.w += __shfl_xor(s.w, 32, 64);
    if (half == 0) {
      uintx2 pk;
      pk.x = cvt_pk_bf16(s.x, s.y);
      pk.y = cvt_pk_bf16(s.z, s.w);
      __builtin_nontemporal_store(pk, reinterpret_cast<uintx2*>(
          &S3[((size_t)(b * 32 + ry) * 32 + 4 * w + t) * 128 + ch4]));
    }
  }
}

// ---------------- MFMA helpers ----------------
// Copy a pre-converted W image (34816 B = 2176 uint4) into LDS wl.
DEVFN void copy_wimg(unsigned short* __restrict__ wl,
                     const unsigned int* __restrict__ img, int tid) {
  uint4* dst = reinterpret_cast<uint4*>(wl);
  const uint4* src = reinterpret_cast<const uint4*>(img);
  for (int i = tid; i < 2176; i += 512)
    dst[i] = src[i];
}

// 8-step (K=128) MFMA tile, stride-16 frags.
DEVFN f32x16 mfma_tile(const unsigned short* __restrict__ xrow,
                       const unsigned short* __restrict__ wrow) {
  f32x16 acc;
  #pragma unroll
  for (int r = 0; r < 16; ++r) acc[r] = 0.f;
  #pragma unroll
  for (int kk = 0; kk < 8; ++kk) {
    const bf16x8 a = *reinterpret_cast<const bf16x8*>(xrow + kk * 16);
    const bf16x8 bb = *reinterpret_cast<const bf16x8*>(wrow + kk * 16);
    acc = __builtin_amdgcn_mfma_f32_32x32x16_bf16(a, bb, acc, 0, 0, 0);
  }
  return acc;
}

// C/D layout (verified m74/m101): col = lane&31, row = (r&3)+8*(r>>2)+4*(l>>5).
DEVFN void write_raw(float* __restrict__ raw, const f32x16 acc,
                     int tg, int cg, int lane) {
  const int n  = cg * 32 + (lane & 31);
  const int mb = tg * 32 + 4 * (lane >> 5);
  #pragma unroll
  for (int r = 0; r < 16; ++r) {
    const int mm = mb + (r & 3) + 8 * (r >> 2);
    raw[mm * 132 + n] = acc[r];
  }
}

// ---------------- Kernel 2: window gather + token_proj (bf16 MFMA) ----------
__global__ __launch_bounds__(512) void k_tok(const unsigned short* __restrict__ S3,
    const unsigned int* __restrict__ wimg,
    const float* __restrict__ bt, const float* __restrict__ gt,
    const float* __restrict__ bgt, unsigned short* __restrict__ tok) {
  __shared__ __align__(16) unsigned short xs_bf[64 * 136];
  __shared__ __align__(16) unsigned short wl[128 * 136];
  float* raw = reinterpret_cast<float*>(wl);

  const int tid = threadIdx.x;
  const int t0 = blockIdx.x * 64;
  const int s  = t0 >> 13;
  const int b  = (t0 >> 8) & 31;
  const int wyx = t0 & 255;

  const unsigned short* Sb = S3 + (size_t)b * 131072;
  #pragma unroll
  for (int p = 0; p < 2; ++p) {
    const int i = tid + p * 512;
    const int tt = i >> 4, c8 = (i & 15) * 8;
    const int idx = wyx + tt;
    const int wy = idx >> 4, wx = idx & 15;
    int ry0, ry1, c0, c1;
    if (s == 0) { ry0 = 2 * wy;     ry1 = 2 * wy + 1;        c0 = 2 * wx;     c1 = 2 * wx + 1; }
    else        { ry0 = 2 * wy + 1; ry1 = (2 * wy + 2) & 31; c0 = 2 * wx + 1; c1 = (2 * wx + 2) & 31; }
    const bf16x8 v00 = *reinterpret_cast<const bf16x8*>(Sb + ((size_t)(ry0 * 32 + c0) * 128 + c8));
    const bf16x8 v01 = *reinterpret_cast<const bf16x8*>(Sb + ((size_t)(ry0 * 32 + c1) * 128 + c8));
    const bf16x8 v10 = *reinterpret_cast<const bf16x8*>(Sb + ((size_t)(ry1 * 32 + c0) * 128 + c8));
    const bf16x8 v11 = *reinterpret_cast<const bf16x8*>(Sb + ((size_t)(ry1 * 32 + c1) * 128 + c8));
    float sv[8];
    #pragma unroll
    for (int j = 0; j < 8; ++j) {
      sv[j] = (bf2f((unsigned short)v00[j]) + bf2f((unsigned short)v01[j]) +
               bf2f((unsigned short)v10[j]) + bf2f((unsigned short)v11[j])) * (1.f / 36.f);
    }
    unsigned int* dst = reinterpret_cast<unsigned int*>(&xs_bf[tt * 136 + c8]);
    #pragma unroll
    for (int j = 0; j < 4; ++j)
      dst[j] = cvt_pk_bf16(sv[2 * j], sv[2 * j + 1]);
  }
  copy_wimg(wl, wimg, tid);
  __syncthreads();

  const int lane = tid & 63;
  const int w = tid >> 6;
  const int tg = w >> 2, cg = w & 3;
  const unsigned short* xrow = &xs_bf[(tg * 32 + (lane & 31)) * 136 + 8 * (lane >> 5)];
  const unsigned short* wrow = &wl[(cg * 32 + (lane & 31)) * 136 + 8 * (lane >> 5)];

  const f32x16 acc = mfma_tile(xrow, wrow);
  __syncthreads();
  write_raw(raw, acc, tg, cg, lane);
  __syncthreads();

  {
    const int tt = tid >> 3, cb = tid & 7;
    float v[16];
    float s2 = 0.f, q = 0.f;
    #pragma unroll
    for (int i = 0; i < 4; ++i) {
      const int col = 4 * cb + 32 * i;
      const float4 rv = *reinterpret_cast<const float4*>(&raw[tt * 132 + col]);
      const float4 bv = *reinterpret_cast<const float4*>(bt + col);
      v[4 * i + 0] = rv.x + bv.x; v[4 * i + 1] = rv.y + bv.y;
      v[4 * i + 2] = rv.z + bv.z; v[4 * i + 3] = rv.w + bv.w;
    }
    #pragma unroll
    for (int e = 0; e < 16; ++e) { s2 += v[e]; q += v[e] * v[e]; }
    s2 += __shfl_xor(s2, 1, 8); q += __shfl_xor(q, 1, 8);
    s2 += __shfl_xor(s2, 2, 8); q += __shfl_xor(q, 2, 8);
    s2 += __shfl_xor(s2, 4, 8); q += __shfl_xor(q, 4, 8);
    const float mean = s2 * (1.f / 128.f);
    const float var  = q * (1.f / 128.f) - mean * mean;
    const float inv  = rsqrtf(var + 1e-5f);
    #pragma unroll
    for (int i = 0; i < 4; ++i) {
      const int col = 4 * cb + 32 * i;
      const float4 gv = *reinterpret_cast<const float4*>(gt + col);
      const float4 ev = *reinterpret_cast<const float4*>(bgt + col);
      const float o0 = gelu_fast((v[4 * i + 0] - mean) * inv * gv.x + ev.x);
      const float o1 = gelu_fast((v[4 * i + 1] - mean) * inv * gv.y + ev.y);
      const float o2 = gelu_fast((v[4 * i + 2] - mean) * inv * gv.z + ev.z);
      const float o3 = gelu_fast((v[4 * i + 3] - mean) * inv * gv.w + ev.w);
      uintx2 pk;
      pk.x = cvt_pk_bf16(o0, o1);
      pk.y = cvt_pk_bf16(o2, o3);
      __builtin_nontemporal_store(pk, reinterpret_cast<uintx2*>(
          tok + (size_t)(t0 + tt) * 128 + col));
    }
  }
}

// -------- Kernel 3: fuse + out_proj via bf16 MFMA + expand --------
// grid = 32*16 (b, m), 512 thr = 8 waves; wave (tg=w>>2, cg=w&3).
__global__ __launch_bounds__(512) void k_fuse_out(const unsigned short* __restrict__ tok,
    const unsigned int* __restrict__ wimgF, const float* __restrict__ bfv,
    const float* __restrict__ gf, const float* __restrict__ bgf,
    const unsigned int* __restrict__ wimgO, const float* __restrict__ bo,
    const float* __restrict__ go, const float* __restrict__ bgo,
    const float* __restrict__ mask, float* __restrict__ out) {
  __shared__ __align__(16) unsigned short xs_bf[64 * 136];   // 17408 B
  __shared__ __align__(16) unsigned short wl[128 * 136];     // 34816 B
  float* raw = reinterpret_cast<float*>(wl);                 // [64][132] f32

  const int tid = threadIdx.x;
  const int b = blockIdx.x >> 4;
  const int m = blockIdx.x & 15;
  const int lane = tid & 63;
  const int w = tid >> 6;
  const int tg = w >> 2, cg = w & 3;

  const unsigned short* tokR = tok + (size_t)b * 32768 + (size_t)m * 2048;
  const unsigned short* tokS = tok + 1048576 + (size_t)b * 32768;

  // Phase 0: gather reg+sh (bf16) -> bf16 xs ; copy Wf image.
  #pragma unroll
  for (int p = 0; p < 2; ++p) {
    const int i = tid + p * 512;
    const int t = i >> 4, c8 = (i & 15) * 8;
    const int gx = t & 31, gy = 2 * m + (t >> 5);
    const int wx  = gx >> 1;
    const int wxs = ((gx + 31) & 31) >> 1;
    const int wys = ((gy + 31) & 31) >> 1;
    const bf16x8 pr = *reinterpret_cast<const bf16x8*>(tokR + (size_t)wx * 128 + c8);
    const bf16x8 ps = *reinterpret_cast<const bf16x8*>(tokS + (size_t)(wys * 16 + wxs) * 128 + c8);
    float sv[8];
    #pragma unroll
    for (int j = 0; j < 8; ++j)
      sv[j] = bf2f((unsigned short)pr[j]) + bf2f((unsigned short)ps[j]);
    unsigned int* dst = reinterpret_cast<unsigned int*>(&xs_bf[t * 136 + c8]);
    #pragma unroll
    for (int j = 0; j < 4; ++j)
      dst[j] = cvt_pk_bf16(sv[2 * j], sv[2 * j + 1]);
  }
  copy_wimg(wl, wimgF, tid);
  __syncthreads();

  const unsigned short* xrow = &xs_bf[(tg * 32 + (lane & 31)) * 136 + 8 * (lane >> 5)];
  const unsigned short* wrow = &wl[(cg * 32 + (lane & 31)) * 136 + 8 * (lane >> 5)];

  // Phase 1: fuse GEMM.
  const f32x16 acc1 = mfma_tile(xrow, wrow);
  __syncthreads();                        // all wl reads done before raw write
  write_raw(raw, acc1, tg, cg, lane);
  __syncthreads();

  // Phase 2: LN+GELU(ctx) -> bf16 back into xs_bf. 8 threads/token.
  {
    const int tt = tid >> 3, cb = tid & 7;
    float v[16];
    float s = 0.f, q = 0.f;
    #pragma unroll
    for (int i = 0; i < 4; ++i) {
      const int col = 4 * cb + 32 * i;
      const float4 rv = *reinterpret_cast<const float4*>(&raw[tt * 132 + col]);
      const float4 bv = *reinterpret_cast<const float4*>(bfv + col);
      v[4 * i + 0] = rv.x + bv.x; v[4 * i + 1] = rv.y + bv.y;
      v[4 * i + 2] = rv.z + bv.z; v[4 * i + 3] = rv.w + bv.w;
    }
    #pragma unroll
    for (int e = 0; e < 16; ++e) { s += v[e]; q += v[e] * v[e]; }
    s += __shfl_xor(s, 1, 8); q += __shfl_xor(q, 1, 8);
    s += __shfl_xor(s, 2, 8); q += __shfl_xor(q, 2, 8);
    s += __shfl_xor(s, 4, 8); q += __shfl_xor(q, 4, 8);
    const float mean = s * (1.f / 128.f);
    const float var  = q * (1.f / 128.f) - mean * mean;
    const float inv  = rsqrtf(var + 1e-5f);
    #pragma unroll
    for (int i = 0; i < 4; ++i) {
      const int col = 4 * cb + 32 * i;
      const float4 gv = *reinterpret_cast<const float4*>(gf + col);
      const float4 ev = *reinterpret_cast<const float4*>(bgf + col);
      const float o0 = gelu_fast((v[4 * i + 0] - mean) * inv * gv.x + ev.x);
      const float o1 = gelu_fast((v[4 * i + 1] - mean) * inv * gv.y + ev.y);
      const float o2 = gelu_fast((v[4 * i + 2] - mean) * inv * gv.z + ev.z);
      const float o3 = gelu_fast((v[4 * i + 3] - mean) * inv * gv.w + ev.w);
      uintx2 pk;
      pk.x = cvt_pk_bf16(o0, o1);
      pk.y = cvt_pk_bf16(o2, o3);
      *reinterpret_cast<uintx2*>(&xs_bf[tt * 136 + col]) = pk;
    }
  }
  __syncthreads();                        // ctx complete; raw reads done
  copy_wimg(wl, wimgO, tid);
  __syncthreads();

  // Phase 3: out_proj GEMM.
  const f32x16 acc2 = mfma_tile(xrow, wrow);
  __syncthreads();
  write_raw(raw, acc2, tg, cg, lane);
  __syncthreads();

  // Phase 4: LN+GELU(out) + mask + 3x3 expand nontemporal stores.
  {
    const int tt = tid >> 3, cb = tid & 7;
    float v[16];
    float s = 0.f, q = 0.f;
    #pragma unroll
    for (int i = 0; i < 4; ++i) {
      const int col = 4 * cb + 32 * i;
      const float4 rv = *reinterpret_cast<const float4*>(&raw[tt * 132 + col]);
      const float4 bv = *reinterpret_cast<const float4*>(bo + col);
      v[4 * i + 0] = rv.x + bv.x; v[4 * i + 1] = rv.y + bv.y;
      v[4 * i + 2] = rv.z + bv.z; v[4 * i + 3] = rv.w + bv.w;
    }
    #pragma unroll
    for (int e = 0; e < 16; ++e) { s += v[e]; q += v[e] * v[e]; }
    s += __shfl_xor(s, 1, 8); q += __shfl_xor(q, 1, 8);
    s += __shfl_xor(s, 2, 8); q += __shfl_xor(q, 2, 8);
    s += __shfl_xor(s, 4, 8); q += __shfl_xor(q, 4, 8);
    const float mean = s * (1.f / 128.f);
    const float var  = q * (1.f / 128.f) - mean * mean;
    const float inv  = rsqrtf(var + 1e-5f);
    #pragma unroll
    for (int i = 0; i < 4; ++i) {
      const int col = 4 * cb + 32 * i;
      const float4 gv = *reinterpret_cast<const float4*>(go + col);
      const float4 ev = *reinterpret_cast<const float4*>(bgo + col);
      v[4 * i + 0] = gelu_fast((v[4 * i + 0] - mean) * inv * gv.x + ev.x);
      v[4 * i + 1] = gelu_fast((v[4 * i + 1] - mean) * inv * gv.y + ev.y);
      v[4 * i + 2] = gelu_fast((v[4 * i + 2] - mean) * inv * gv.z + ev.z);
      v[4 * i + 3] = gelu_fast((v[4 * i + 3] - mean) * inv * gv.w + ev.w);
    }
    const int gx = tt & 31, gy = 2 * m + (tt >> 5);
    #pragma unroll
    for (int py = 0; py < 3; ++py) {
      const int y = 3 * gy + py;
      #pragma unroll
      for (int px = 0; px < 3; ++px) {
        const int x = 3 * gx + px;
        const size_t pix = (size_t)b * 9216 + (size_t)y * 96 + x;
        const float mv = mask[pix];
        #pragma unroll
        for (int i = 0; i < 4; ++i) {
          const int col = 4 * cb + 32 * i;
          floatx4 ov;
          ov.x = v[4 * i + 0] * mv; ov.y = v[4 * i + 1] * mv;
          ov.z = v[4 * i + 2] * mv; ov.w = v[4 * i + 3] * mv;
          __builtin_nontemporal_store(ov,
              reinterpret_cast<floatx4*>(out + pix * 128 + col));
        }
      }
    }
  }
}

extern "C" void kernel_launch(void* const* d_in, const int* in_sizes, int n_in,
                              void* d_out, int out_size, void* d_ws, size_t ws_size,
                              hipStream_t stream) {
  (void)in_sizes; (void)n_in; (void)out_size; (void)ws_size;
  const float* h    = (const float*)d_in[0];
  const float* mask = (const float*)d_in[1];
  const float* Wt   = (const float*)d_in[2];
  const float* bt   = (const float*)d_in[3];
  const float* gt   = (const float*)d_in[4];
  const float* bgt  = (const float*)d_in[5];
  const float* Wf   = (const float*)d_in[6];
  const float* bfv  = (const float*)d_in[7];
  const float* gf   = (const float*)d_in[8];
  const float* bgf  = (const float*)d_in[9];
  const float* Wo   = (const float*)d_in[10];
  const float* bo   = (const float*)d_in[11];
  const float* go   = (const float*)d_in[12];
  const float* bgo  = (const float*)d_in[13];

  unsigned short* S3  = (unsigned short*)d_ws;                          // 8 MB
  unsigned short* tok = (unsigned short*)((char*)d_ws + (size_t)8 * 1024 * 1024);  // 4 MB
  unsigned int* imgs  = (unsigned int*)((char*)d_ws + (size_t)12 * 1024 * 1024);   // 102 KB
  float* out = (float*)d_out;

  hipLaunchKernelGGL(k_tile3, dim3(1027), dim3(512), 0, stream,
                     h, Wt, Wf, Wo, S3, imgs);
  hipLaunchKernelGGL(k_tok, dim3(256), dim3(512), 0, stream,
                     S3, imgs, bt, gt, bgt, tok);
  hipLaunchKernelGGL(k_fuse_out, dim3(512), dim3(512), 0, stream,
                     tok, imgs + 8704, bfv, gf, bgf,
                     imgs + 17408, bo, go, bgo, mask, out);
}